// Round 1
// baseline (421.229 us; speedup 1.0000x reference)
//
#include <hip/hip_runtime.h>
#include <stdint.h>

#define SEQ 2048
#define DIM 1024
#define NB 4
#define MTOT (NB*SEQ)

typedef __attribute__((ext_vector_type(8))) short short8;
typedef __attribute__((ext_vector_type(4))) float f32x4;

__device__ __forceinline__ unsigned short f2b(float f) {
    union { float f; unsigned int u; } v; v.f = f;
    return (unsigned short)((v.u + 0x7FFFu + ((v.u >> 16) & 1u)) >> 16);
}

// fp32 -> bf16 cast, 8 elems/thread
__global__ __launch_bounds__(256)
void cast_kernel(const float* __restrict__ in, unsigned short* __restrict__ out, int nchunk) {
    int i = blockIdx.x * 256 + threadIdx.x;
    if (i >= nchunk) return;
    float4 a = ((const float4*)in)[i*2];
    float4 b = ((const float4*)in)[i*2+1];
    union { unsigned short u[8]; uint4 v; } r;
    r.u[0]=f2b(a.x); r.u[1]=f2b(a.y); r.u[2]=f2b(a.z); r.u[3]=f2b(a.w);
    r.u[4]=f2b(b.x); r.u[5]=f2b(b.y); r.u[6]=f2b(b.z); r.u[7]=f2b(b.w);
    ((uint4*)out)[i] = r.v;
}

// fp32 [R][C] -> bf16 [C][R]
__global__ __launch_bounds__(256)
void transpose_cast_f32(const float* __restrict__ in, unsigned short* __restrict__ out, int R, int C) {
    __shared__ unsigned short tile[64][66];
    int tpc = C >> 6;
    int tr = (blockIdx.x / tpc) << 6;
    int tc = (blockIdx.x % tpc) << 6;
    int t = threadIdx.x;
    #pragma unroll
    for (int i = 0; i < 16; i++) {
        int idx = t + i*256;
        int r = idx >> 6, c = idx & 63;
        tile[r][c] = f2b(in[(size_t)(tr + r)*C + tc + c]);
    }
    __syncthreads();
    #pragma unroll
    for (int i = 0; i < 16; i++) {
        int idx = t + i*256;
        int r = idx >> 6, c = idx & 63;
        out[(size_t)(tc + r)*R + tr + c] = tile[c][r];
    }
}

// bf16 [R][C] -> bf16 [C][R], batched via blockIdx.y
__global__ __launch_bounds__(256)
void transpose_b16(const unsigned short* __restrict__ in0, unsigned short* __restrict__ out0, int R, int C) {
    const unsigned short* in = in0 + (size_t)blockIdx.y * R * C;
    unsigned short* out = out0 + (size_t)blockIdx.y * R * C;
    __shared__ unsigned short tile[64][66];
    int tpc = C >> 6;
    int tr = (blockIdx.x / tpc) << 6;
    int tc = (blockIdx.x % tpc) << 6;
    int t = threadIdx.x;
    #pragma unroll
    for (int i = 0; i < 16; i++) {
        int idx = t + i*256;
        int r = idx >> 6, c = idx & 63;
        tile[r][c] = in[(size_t)(tr + r)*C + tc + c];
    }
    __syncthreads();
    #pragma unroll
    for (int i = 0; i < 16; i++) {
        int idx = t + i*256;
        int r = idx >> 6, c = idx & 63;
        out[(size_t)(tc + r)*R + tr + c] = tile[c][r];
    }
}

// C[M,N] = A[M,K] @ Bt[N,K]^T   (both row-major, bf16), fp32 accum.
// MODE 0: C = bf16(acc + bias[col])   (ushort out)
// MODE 1: C = f32(acc * scale)
// MODE 2: C = f32(acc)
template<int MODE>
__global__ __launch_bounds__(256, 2)
void gemm_nt(const unsigned short* __restrict__ A, int lda,
             const unsigned short* __restrict__ Bt, int ldb,
             const float* __restrict__ bias,
             void* __restrict__ Cout,
             int M, int N, int K, float scale)
{
    __shared__ __align__(16) unsigned short As[128][72];
    __shared__ __align__(16) unsigned short Bs[128][72];
    int nbn = N >> 7;
    int bm = (int)blockIdx.x / nbn;
    int bn = (int)blockIdx.x % nbn;
    int tid = threadIdx.x;
    int lane = tid & 63;
    int wid = tid >> 6;
    int wm = (wid >> 1) * 64, wn = (wid & 1) * 64;
    int lr = lane & 15;
    int lk = (lane >> 4) * 8;

    f32x4 acc[4][4];
    #pragma unroll
    for (int i = 0; i < 4; i++)
        #pragma unroll
        for (int j = 0; j < 4; j++) acc[i][j] = (f32x4){0.f,0.f,0.f,0.f};

    const unsigned short* Ab = A + (size_t)(bm*128)*lda;
    const unsigned short* Bb = Bt + (size_t)(bn*128)*ldb;

    for (int k0 = 0; k0 < K; k0 += 64) {
        #pragma unroll
        for (int i = 0; i < 4; i++) {
            int c = tid + i*256;
            int row = c >> 3, cc = (c & 7) << 3;
            *(short8*)&As[row][cc] = *(const short8*)(Ab + (size_t)row*lda + k0 + cc);
        }
        #pragma unroll
        for (int i = 0; i < 4; i++) {
            int c = tid + i*256;
            int row = c >> 3, cc = (c & 7) << 3;
            *(short8*)&Bs[row][cc] = *(const short8*)(Bb + (size_t)row*ldb + k0 + cc);
        }
        __syncthreads();
        #pragma unroll
        for (int ks = 0; ks < 2; ks++) {
            short8 af[4], bfr[4];
            #pragma unroll
            for (int mf = 0; mf < 4; mf++)
                af[mf] = *(const short8*)&As[wm + mf*16 + lr][ks*32 + lk];
            #pragma unroll
            for (int nf = 0; nf < 4; nf++)
                bfr[nf] = *(const short8*)&Bs[wn + nf*16 + lr][ks*32 + lk];
            #pragma unroll
            for (int mf = 0; mf < 4; mf++)
                #pragma unroll
                for (int nf = 0; nf < 4; nf++)
                    acc[mf][nf] = __builtin_amdgcn_mfma_f32_16x16x32_bf16(af[mf], bfr[nf], acc[mf][nf], 0, 0, 0);
        }
        __syncthreads();
    }

    int r0 = (lane >> 4) << 2;
    #pragma unroll
    for (int mf = 0; mf < 4; mf++) {
        #pragma unroll
        for (int nf = 0; nf < 4; nf++) {
            int col = bn*128 + wn + nf*16 + lr;
            float badd = (MODE == 0) ? bias[col] : 0.f;
            #pragma unroll
            for (int r = 0; r < 4; r++) {
                int row = bm*128 + wm + mf*16 + r0 + r;
                float v = acc[mf][nf][r];
                if (MODE == 0) {
                    ((unsigned short*)Cout)[(size_t)row*N + col] = f2b(v + badd);
                } else if (MODE == 1) {
                    ((float*)Cout)[(size_t)row*N + col] = v * scale;
                } else {
                    ((float*)Cout)[(size_t)row*N + col] = v;
                }
            }
        }
    }
}

// row softmax over 2048 fp32 scores; writes bf16 probs IN-PLACE at row start
__global__ __launch_bounds__(256)
void softmax_kernel(float* __restrict__ S) {
    int row = blockIdx.x;
    float* srow = S + (size_t)row * SEQ;
    int t = threadIdx.x;
    float4 v0 = ((const float4*)srow)[t*2];
    float4 v1 = ((const float4*)srow)[t*2+1];
    float x[8] = {v0.x,v0.y,v0.z,v0.w,v1.x,v1.y,v1.z,v1.w};
    float m = fmaxf(fmaxf(fmaxf(x[0],x[1]),fmaxf(x[2],x[3])),
                    fmaxf(fmaxf(x[4],x[5]),fmaxf(x[6],x[7])));
    #pragma unroll
    for (int off = 32; off; off >>= 1) m = fmaxf(m, __shfl_xor(m, off));
    __shared__ float redm[4], reds[4];
    int w = t >> 6;
    if ((t & 63) == 0) redm[w] = m;
    __syncthreads();
    m = fmaxf(fmaxf(redm[0], redm[1]), fmaxf(redm[2], redm[3]));
    float e[8]; float s = 0.f;
    #pragma unroll
    for (int i = 0; i < 8; i++) { e[i] = __expf(x[i] - m); s += e[i]; }
    #pragma unroll
    for (int off = 32; off; off >>= 1) s += __shfl_xor(s, off);
    if ((t & 63) == 0) reds[w] = s;
    __syncthreads();
    float inv = 1.0f / (reds[0]+reds[1]+reds[2]+reds[3]);
    union { unsigned short u[8]; uint4 v; } r;
    #pragma unroll
    for (int i = 0; i < 8; i++) r.u[i] = f2b(e[i] * inv);
    ((uint4*)srow)[t] = r.v;   // all loads done before 2nd barrier -> in-place safe
}

extern "C" void kernel_launch(void* const* d_in, const int* in_sizes, int n_in,
                              void* d_out, int out_size, void* d_ws, size_t ws_size,
                              hipStream_t stream)
{
    (void)in_sizes; (void)n_in; (void)out_size; (void)ws_size;
    const float* x  = (const float*)d_in[0];
    const float* Wq = (const float*)d_in[1];
    const float* bq = (const float*)d_in[2];
    const float* Wk = (const float*)d_in[3];
    const float* bk = (const float*)d_in[4];
    const float* Wv = (const float*)d_in[5];
    const float* bv = (const float*)d_in[6];
    float* out = (float*)d_out;

    // workspace layout (bf16 unless noted); vt overlays xb (dead after QKV gemms)
    unsigned short* xb  = (unsigned short*)d_ws;            // [8192][1024]
    unsigned short* wqt = xb + (size_t)MTOT*DIM;            // [1024][1024] (W^T)
    unsigned short* wkt = wqt + (size_t)DIM*DIM;
    unsigned short* wvt = wkt + (size_t)DIM*DIM;
    unsigned short* qb  = wvt + (size_t)DIM*DIM;            // [8192][1024]
    unsigned short* kb  = qb + (size_t)MTOT*DIM;
    unsigned short* vb  = kb + (size_t)MTOT*DIM;
    float* scores       = (float*)(vb + (size_t)MTOT*DIM);  // [2048][2048] fp32 (per batch)
    unsigned short* vt  = xb;                               // [4][1024][2048] (v^T per batch)

    cast_kernel<<<MTOT*DIM/8/256, 256, 0, stream>>>(x, xb, MTOT*DIM/8);
    transpose_cast_f32<<<256, 256, 0, stream>>>(Wq, wqt, DIM, DIM);
    transpose_cast_f32<<<256, 256, 0, stream>>>(Wk, wkt, DIM, DIM);
    transpose_cast_f32<<<256, 256, 0, stream>>>(Wv, wvt, DIM, DIM);

    dim3 gq((MTOT/128)*(DIM/128));
    gemm_nt<0><<<gq, 256, 0, stream>>>(xb, DIM, wqt, DIM, bq, qb, MTOT, DIM, DIM, 1.f);
    gemm_nt<0><<<gq, 256, 0, stream>>>(xb, DIM, wkt, DIM, bk, kb, MTOT, DIM, DIM, 1.f);
    gemm_nt<0><<<gq, 256, 0, stream>>>(xb, DIM, wvt, DIM, bv, vb, MTOT, DIM, DIM, 1.f);

    transpose_b16<<<dim3((SEQ/64)*(DIM/64), NB), 256, 0, stream>>>(vb, vt, SEQ, DIM);

    const float scl = 1.0f / 32.0f;   // 1/sqrt(1024)
    for (int b = 0; b < NB; b++) {
        const unsigned short* qbb = qb + (size_t)b*SEQ*DIM;
        const unsigned short* kbb = kb + (size_t)b*SEQ*DIM;
        const unsigned short* vtb = vt + (size_t)b*DIM*SEQ;
        gemm_nt<1><<<dim3((SEQ/128)*(SEQ/128)), 256, 0, stream>>>(
            qbb, DIM, kbb, DIM, nullptr, scores, SEQ, SEQ, DIM, scl);
        softmax_kernel<<<SEQ, 256, 0, stream>>>(scores);
        gemm_nt<2><<<dim3((SEQ/128)*(DIM/128)), 256, 0, stream>>>(
            (const unsigned short*)scores, 2*SEQ, vtb, SEQ, nullptr,
            out + (size_t)b*SEQ*DIM, SEQ, DIM, SEQ, 1.f);
    }
}

// Round 2
// 213.307 us; speedup vs baseline: 1.9748x; 1.9748x over previous
//
#include <hip/hip_runtime.h>
#include <stdint.h>

#define SEQ 2048
#define DIM 1024
#define NB 4
#define MTOT (NB*SEQ)
#define QKVN (3*DIM)

typedef __attribute__((ext_vector_type(8))) short short8;
typedef __attribute__((ext_vector_type(4))) float f32x4;

__device__ __forceinline__ unsigned short f2b(float f) {
    union { float f; unsigned int u; } v; v.f = f;
    return (unsigned short)((v.u + 0x7FFFu + ((v.u >> 16) & 1u)) >> 16);
}

// async global->LDS, 16B per lane. LDS dest must be wave-uniform; HW adds lane*16.
__device__ __forceinline__ void gload_lds16(const unsigned short* g, unsigned short* l) {
    __builtin_amdgcn_global_load_lds(
        (const __attribute__((address_space(1))) void*)g,
        (__attribute__((address_space(3))) void*)l, 16, 0, 0);
}

// fp32 -> bf16 cast, 8 elems/thread
__global__ __launch_bounds__(256)
void cast_kernel(const float* __restrict__ in, unsigned short* __restrict__ out, int nchunk) {
    int i = blockIdx.x * 256 + threadIdx.x;
    if (i >= nchunk) return;
    float4 a = ((const float4*)in)[i*2];
    float4 b = ((const float4*)in)[i*2+1];
    union { unsigned short u[8]; uint4 v; } r;
    r.u[0]=f2b(a.x); r.u[1]=f2b(a.y); r.u[2]=f2b(a.z); r.u[3]=f2b(a.w);
    r.u[4]=f2b(b.x); r.u[5]=f2b(b.y); r.u[6]=f2b(b.z); r.u[7]=f2b(b.w);
    ((uint4*)out)[i] = r.v;
}

// fp32 [R][C] -> bf16 [C][R]
__global__ __launch_bounds__(256)
void transpose_cast_f32(const float* __restrict__ in, unsigned short* __restrict__ out, int R, int C) {
    __shared__ unsigned short tile[64][66];
    int tpc = C >> 6;
    int tr = (blockIdx.x / tpc) << 6;
    int tc = (blockIdx.x % tpc) << 6;
    int t = threadIdx.x;
    #pragma unroll
    for (int i = 0; i < 16; i++) {
        int idx = t + i*256;
        int r = idx >> 6, c = idx & 63;
        tile[r][c] = f2b(in[(size_t)(tr + r)*C + tc + c]);
    }
    __syncthreads();
    #pragma unroll
    for (int i = 0; i < 16; i++) {
        int idx = t + i*256;
        int r = idx >> 6, c = idx & 63;
        out[(size_t)(tc + r)*R + tr + c] = tile[c][r];
    }
}

// bf16 [.][ldin] -> bf16 [.][ldout] transpose, batched via blockIdx.y
__global__ __launch_bounds__(256)
void transpose_b16(const unsigned short* __restrict__ in0, size_t sIn, int ldin,
                   unsigned short* __restrict__ out0, size_t sOut, int ldout, int tpc) {
    const unsigned short* in = in0 + sIn * blockIdx.y;
    unsigned short* out = out0 + sOut * blockIdx.y;
    __shared__ unsigned short tile[64][66];
    int tr = ((int)blockIdx.x / tpc) << 6;
    int tc = ((int)blockIdx.x % tpc) << 6;
    int t = threadIdx.x;
    #pragma unroll
    for (int i = 0; i < 16; i++) {
        int idx = t + i*256;
        int r = idx >> 6, c = idx & 63;
        tile[r][c] = in[(size_t)(tr + r)*ldin + tc + c];
    }
    __syncthreads();
    #pragma unroll
    for (int i = 0; i < 16; i++) {
        int idx = t + i*256;
        int r = idx >> 6, c = idx & 63;
        out[(size_t)(tc + r)*ldout + tr + c] = tile[c][r];
    }
}

__global__ __launch_bounds__(256)
void bias_concat(const float* __restrict__ bq, const float* __restrict__ bk,
                 const float* __restrict__ bv, float* __restrict__ o) {
    int i = blockIdx.x*256 + threadIdx.x;
    float v = (i < DIM) ? bq[i] : ((i < 2*DIM) ? bk[i-DIM] : bv[i-2*DIM]);
    o[i] = v;
}

// C = A[M,K] @ Bt[N,K]^T, bf16 in / fp32 accum. m97 structure:
// 128x128 tile, BK=64, linear LDS staged by global_load_lds width-16.
// MODE 0: bf16(acc + bias[col]); MODE 1: f32(acc*scale); MODE 2: f32(acc)
// batched over blockIdx.y with element strides sA/sB/sC.
template<int MODE>
__global__ __launch_bounds__(256, 2)
void gemm_nt(const unsigned short* __restrict__ A, int lda, size_t sA,
             const unsigned short* __restrict__ Bt, int ldb, size_t sB,
             const float* __restrict__ bias,
             void* __restrict__ Cout, int ldc, size_t sC,
             int N, int K, float scale)
{
    __shared__ __align__(16) unsigned short As[128][64];
    __shared__ __align__(16) unsigned short Bs[128][64];
    int nbn = N >> 7;
    int bm = (int)blockIdx.x / nbn;
    int bn = (int)blockIdx.x % nbn;
    int bz = blockIdx.y;
    int tid = threadIdx.x;
    int lane = tid & 63;
    int wid  = tid >> 6;
    int wm = (wid >> 1) * 64, wn = (wid & 1) * 64;
    int lr = lane & 15;
    int lk = (lane >> 4) * 8;
    int srow = lane >> 3;          // row within wave's 8-row staging group
    int scol = (lane & 7) * 8;     // col (shorts) within row

    f32x4 acc[4][4];
    #pragma unroll
    for (int i = 0; i < 4; i++)
        #pragma unroll
        for (int j = 0; j < 4; j++) acc[i][j] = (f32x4){0.f,0.f,0.f,0.f};

    const unsigned short* Ab = A + sA*bz + (size_t)(bm*128)*lda;
    const unsigned short* Bb = Bt + sB*bz + (size_t)(bn*128)*ldb;

    for (int k0 = 0; k0 < K; k0 += 64) {
        #pragma unroll
        for (int r = 0; r < 4; r++) {
            int rowg = r*32 + wid*8;
            gload_lds16(Ab + (size_t)(rowg + srow)*lda + k0 + scol, &As[rowg][0]);
            gload_lds16(Bb + (size_t)(rowg + srow)*ldb + k0 + scol, &Bs[rowg][0]);
        }
        __syncthreads();   // compiler drains vmcnt(0) before barrier
        #pragma unroll
        for (int ks = 0; ks < 2; ks++) {
            short8 af[4], bfr[4];
            #pragma unroll
            for (int mf = 0; mf < 4; mf++)
                af[mf] = *(const short8*)&As[wm + mf*16 + lr][ks*32 + lk];
            #pragma unroll
            for (int nf = 0; nf < 4; nf++)
                bfr[nf] = *(const short8*)&Bs[wn + nf*16 + lr][ks*32 + lk];
            #pragma unroll
            for (int mf = 0; mf < 4; mf++)
                #pragma unroll
                for (int nf = 0; nf < 4; nf++)
                    acc[mf][nf] = __builtin_amdgcn_mfma_f32_16x16x32_bf16(af[mf], bfr[nf], acc[mf][nf], 0, 0, 0);
        }
        __syncthreads();
    }

    int r0 = (lane >> 4) << 2;
    unsigned short* Cu = (unsigned short*)Cout + sC*bz;
    float* Cf = (float*)Cout + sC*bz;
    #pragma unroll
    for (int mf = 0; mf < 4; mf++) {
        #pragma unroll
        for (int nf = 0; nf < 4; nf++) {
            int col = bn*128 + wn + nf*16 + lr;
            float badd = (MODE == 0) ? bias[col] : 0.f;
            #pragma unroll
            for (int r = 0; r < 4; r++) {
                int row = bm*128 + wm + mf*16 + r0 + r;
                float v = acc[mf][nf][r];
                if (MODE == 0) {
                    Cu[(size_t)row*ldc + col] = f2b(v + badd);
                } else if (MODE == 1) {
                    Cf[(size_t)row*ldc + col] = v * scale;
                } else {
                    Cf[(size_t)row*ldc + col] = v;
                }
            }
        }
    }
}

// row softmax over 2048 fp32 scores; writes bf16 probs IN-PLACE at row start
__global__ __launch_bounds__(256)
void softmax_kernel(float* __restrict__ S) {
    int row = blockIdx.x;
    float* srow = S + (size_t)row * SEQ;
    int t = threadIdx.x;
    float4 v0 = ((const float4*)srow)[t*2];
    float4 v1 = ((const float4*)srow)[t*2+1];
    float x[8] = {v0.x,v0.y,v0.z,v0.w,v1.x,v1.y,v1.z,v1.w};
    float m = fmaxf(fmaxf(fmaxf(x[0],x[1]),fmaxf(x[2],x[3])),
                    fmaxf(fmaxf(x[4],x[5]),fmaxf(x[6],x[7])));
    #pragma unroll
    for (int off = 32; off; off >>= 1) m = fmaxf(m, __shfl_xor(m, off));
    __shared__ float redm[4], reds[4];
    int w = t >> 6;
    if ((t & 63) == 0) redm[w] = m;
    __syncthreads();
    m = fmaxf(fmaxf(redm[0], redm[1]), fmaxf(redm[2], redm[3]));
    float e[8]; float s = 0.f;
    #pragma unroll
    for (int i = 0; i < 8; i++) { e[i] = __expf(x[i] - m); s += e[i]; }
    #pragma unroll
    for (int off = 32; off; off >>= 1) s += __shfl_xor(s, off);
    if ((t & 63) == 0) reds[w] = s;
    __syncthreads();
    float inv = 1.0f / (reds[0]+reds[1]+reds[2]+reds[3]);
    union { unsigned short u[8]; uint4 v; } r;
    #pragma unroll
    for (int i = 0; i < 8; i++) r.u[i] = f2b(e[i] * inv);
    ((uint4*)srow)[t] = r.v;   // all cross-wave reads are pre-barrier -> in-place safe
}

extern "C" void kernel_launch(void* const* d_in, const int* in_sizes, int n_in,
                              void* d_out, int out_size, void* d_ws, size_t ws_size,
                              hipStream_t stream)
{
    (void)in_sizes; (void)n_in; (void)out_size;
    const float* x  = (const float*)d_in[0];
    const float* Wq = (const float*)d_in[1];
    const float* bq = (const float*)d_in[2];
    const float* Wk = (const float*)d_in[3];
    const float* bk = (const float*)d_in[4];
    const float* Wv = (const float*)d_in[5];
    const float* bv = (const float*)d_in[6];
    float* out = (float*)d_out;

    // ws layout:
    //   [qkv 48MB][vt 16MB][biasc 64KB][overlay: xb 16MB + wqkvt 6MB  |  scores bpp*16MB]
    unsigned short* qkv = (unsigned short*)d_ws;                    // [8192][3072]
    unsigned short* vt  = qkv + (size_t)MTOT*QKVN;                  // [4][1024][2048]
    float* biasc = (float*)(vt + (size_t)NB*DIM*SEQ);               // [3072]
    char* ovl = (char*)biasc + 65536;
    unsigned short* xb    = (unsigned short*)ovl;                   // [8192][1024]
    unsigned short* wqkvt = xb + (size_t)MTOT*DIM;                  // [3072][1024]
    float* scores = (float*)ovl;                                    // [bpp][2048][2048]

    size_t base = (size_t)MTOT*QKVN*2 + (size_t)NB*DIM*SEQ*2 + 65536;
    int bpp = 1;
    if (base + 4*(size_t)SEQ*SEQ*4 <= ws_size) bpp = 4;
    else if (base + 2*(size_t)SEQ*SEQ*4 <= ws_size) bpp = 2;

    cast_kernel<<<MTOT*DIM/8/256, 256, 0, stream>>>(x, xb, MTOT*DIM/8);
    transpose_cast_f32<<<256, 256, 0, stream>>>(Wq, wqkvt,             DIM, DIM);
    transpose_cast_f32<<<256, 256, 0, stream>>>(Wk, wqkvt + DIM*DIM,   DIM, DIM);
    transpose_cast_f32<<<256, 256, 0, stream>>>(Wv, wqkvt + 2*DIM*DIM, DIM, DIM);
    bias_concat<<<QKVN/256, 256, 0, stream>>>(bq, bk, bv, biasc);

    // fused QKV projection: [8192,1024] @ [3072,1024]^T -> [8192,3072] bf16 (+bias)
    gemm_nt<0><<<dim3((MTOT/128)*(QKVN/128)), 256, 0, stream>>>(
        xb, DIM, 0, wqkvt, DIM, 0, biasc, qkv, QKVN, 0, QKVN, DIM, 1.f);

    // v^T per batch: [2048,1024] (stride 3072) -> [1024,2048]
    transpose_b16<<<dim3((SEQ/64)*(DIM/64), NB), 256, 0, stream>>>(
        qkv + 2*DIM, (size_t)SEQ*QKVN, QKVN, vt, (size_t)DIM*SEQ, SEQ, DIM/64);

    const float scl = 1.0f / 32.0f;   // 1/sqrt(1024)
    for (int p = 0; p < NB; p += bpp) {
        const unsigned short* qp = qkv + (size_t)p*SEQ*QKVN;
        // scores = (Q @ K^T) * scl  (fp32), all bpp batches in one launch
        gemm_nt<1><<<dim3((SEQ/128)*(SEQ/128), bpp), 256, 0, stream>>>(
            qp,        QKVN, (size_t)SEQ*QKVN,
            qp + DIM,  QKVN, (size_t)SEQ*QKVN,
            nullptr, scores, SEQ, (size_t)SEQ*SEQ, SEQ, DIM, scl);
        softmax_kernel<<<bpp*SEQ, 256, 0, stream>>>(scores);
        // out = P @ V  (P bf16 in-place in scores rows, lda = 4096 shorts)
        gemm_nt<2><<<dim3((SEQ/128)*(DIM/128), bpp), 256, 0, stream>>>(
            (const unsigned short*)scores, 2*SEQ, (size_t)SEQ*2*SEQ,
            vt + (size_t)p*DIM*SEQ,        SEQ,   (size_t)DIM*SEQ,
            nullptr, out + (size_t)p*SEQ*DIM, DIM, (size_t)SEQ*DIM, DIM, SEQ, 1.f);
    }
}